// Round 1
// baseline (151.406 us; speedup 1.0000x reference)
//
#include <hip/hip_runtime.h>

#define NROWS  16384
#define DIM    2048
#define KSEL   64          // TOPK/2 per side
#define FACTOR 6.26f

// Monotone order-preserving float->uint transform:
// ascending x  <=>  ascending u ; all negatives < all positives.
__device__ __forceinline__ unsigned f2ord(float f) {
    unsigned b = __float_as_uint(f);
    unsigned m = ((unsigned)((int)b >> 31)) | 0x80000000u;
    return b ^ m;
}

// Block-wide sum (256 threads = 4 waves). All threads return the total.
__device__ __forceinline__ float block_sum(float v, float* redf) {
    #pragma unroll
    for (int off = 32; off; off >>= 1) v += __shfl_down(v, off);
    __syncthreads();                       // protect redf reuse
    if ((threadIdx.x & 63) == 0) redf[threadIdx.x >> 6] = v;
    __syncthreads();
    return redf[0] + redf[1] + redf[2] + redf[3];
}

// Exclusive scan over the 256 threads' values (rare tie path only).
__device__ int excl_scan256(int v, unsigned* hist) {
    const int tid = threadIdx.x;
    __syncthreads();                       // prior hist users done
    hist[tid] = (unsigned)v;
    __syncthreads();
    for (int off = 1; off < 256; off <<= 1) {
        unsigned t = (tid >= off) ? hist[tid - off] : 0u;
        __syncthreads();
        hist[tid] += t;
        __syncthreads();
    }
    return (int)hist[tid] - v;
}

// Radix-select: exact threshold T (in key space key[e] = u[e]^xm) such that
// the top-k set = { key > T } plus `need` lowest-index elements with key==T.
// eqc = total count of elements with key == T. Block-uniform outputs.
__device__ void radix_select(const unsigned (&u)[8], unsigned xm, int k,
                             unsigned* hist, int* shd,
                             unsigned& T, int& need, int& eqc)
{
    const int tid = threadIdx.x;
    unsigned prefix = 0;
    int remaining = k;
    #pragma unroll
    for (int p = 0; p < 4; ++p) {
        const int shift = 24 - 8 * p;
        const unsigned pmask = (p == 0) ? 0u : (0xFFFFFFFFu << (shift + 8));
        hist[tid] = 0u;
        __syncthreads();                   // barrier 1: hist cleared
        #pragma unroll
        for (int e = 0; e < 8; ++e) {
            unsigned key = u[e] ^ xm;
            if ((key & pmask) == prefix)
                atomicAdd(&hist[(key >> shift) & 255u], 1u);
        }
        __syncthreads();                   // barrier 2: histogram done
        if (tid < 64) {                    // wave 0: suffix scan + pick digit
            const int l = tid;
            unsigned h0 = hist[4*l+0], h1 = hist[4*l+1];
            unsigned h2 = hist[4*l+2], h3 = hist[4*l+3];
            unsigned s3 = h3, s2 = h2 + s3, s1 = h1 + s2, s0 = h0 + s1;
            unsigned tot = s0, run = tot;
            #pragma unroll
            for (int off = 1; off < 64; off <<= 1) {
                unsigned v = __shfl_down(run, off);
                if (l + off < 64) run += v;
            }
            unsigned add = run - tot;      // sum over lanes > l  (== sfx[4l+4])
            unsigned f0 = s0 + add, f1 = s1 + add, f2 = s2 + add, f3 = s3 + add;
            const unsigned r = (unsigned)remaining;
            unsigned ab3 = (l == 63) ? 0u : add;
            if (f3 >= r && ab3 < r) { shd[0] = 4*l+3; shd[1] = (int)ab3; shd[2] = (int)(f3 - ab3); }
            if (f2 >= r && f3 < r)  { shd[0] = 4*l+2; shd[1] = (int)f3;  shd[2] = (int)(f2 - f3); }
            if (f1 >= r && f2 < r)  { shd[0] = 4*l+1; shd[1] = (int)f2;  shd[2] = (int)(f1 - f2); }
            if (f0 >= r && f1 < r)  { shd[0] = 4*l+0; shd[1] = (int)f1;  shd[2] = (int)(f0 - f1); }
        }
        __syncthreads();                   // barrier 3: digit published
        const int d = shd[0];
        remaining -= shd[1];
        eqc = shd[2];                      // meaningful after last pass
        prefix |= ((unsigned)d) << shift;
    }
    T = prefix;
    need = remaining;                      // in [1, eqc]
}

// Winner bitmask over this thread's 8 elements for one side.
__device__ unsigned classify(const unsigned (&u)[8], unsigned xm,
                             unsigned T, int need, int eqc, unsigned* hist)
{
    unsigned win = 0;
    if (eqc == need) {                     // fast path: all ties included
        #pragma unroll
        for (int e = 0; e < 8; ++e)
            if ((u[e] ^ xm) >= T) win |= 1u << e;
    } else {                               // exact lowest-index tie-break
        int myeq = 0;
        #pragma unroll
        for (int e = 0; e < 8; ++e) myeq += ((u[e] ^ xm) == T);
        int base = excl_scan256(myeq, hist);
        #pragma unroll
        for (int e = 0; e < 8; ++e) {      // e ascending == global idx ascending
            unsigned key = u[e] ^ xm;
            if (key > T) win |= 1u << e;
            else if (key == T) { if (base < need) win |= 1u << e; ++base; }
        }
    }
    return win;
}

__global__ __launch_bounds__(256)
void kcomp_kernel(const float* __restrict__ xin, float* __restrict__ out)
{
    __shared__ unsigned hist[256];
    __shared__ int shd[3];
    __shared__ float redf[4];

    const int tid = threadIdx.x;
    const size_t rowbase = (size_t)blockIdx.x * DIM;
    const float4* pin = (const float4*)(xin + rowbase);

    // thread t owns consecutive elements [8t, 8t+8)
    float4 a = pin[2 * tid];
    float4 b = pin[2 * tid + 1];
    float xv[8] = {a.x, a.y, a.z, a.w, b.x, b.y, b.z, b.w};
    unsigned u[8];
    #pragma unroll
    for (int e = 0; e < 8; ++e) u[e] = f2ord(xv[e]);

    // top-64 of u  -> largest positives ; top-64 of ~u -> most negative
    unsigned Tp, Tn; int needP, eqcP, needN, eqcN;
    radix_select(u, 0u,          KSEL, hist, shd, Tp, needP, eqcP);
    radix_select(u, 0xFFFFFFFFu, KSEL, hist, shd, Tn, needN, eqcN);

    unsigned winP = classify(u, 0u,          Tp, needP, eqcP, hist);
    unsigned winN = classify(u, 0xFFFFFFFFu, Tn, needN, eqcN, hist);

    // loser energy (positives not in top-k, negatives not in bottom-k)
    float lp = 0.f, ln = 0.f;
    #pragma unroll
    for (int e = 0; e < 8; ++e) {
        float x = xv[e];
        if (!((winP >> e) & 1u)) lp += fmaxf(x, 0.f);
        if (!((winN >> e) & 1u)) ln += fmaxf(-x, 0.f);
    }
    float Ptmp = FACTOR * block_sum(lp, redf);
    float Ntmp = FACTOR * block_sum(ln, redf);

    // out = [winP]*(max(x,0)+Ptmp) - [winN]*(max(-x,0)+Ntmp)
    float o[8];
    #pragma unroll
    for (int e = 0; e < 8; ++e) {
        float x = xv[e];
        float v = 0.f;
        if ((winP >> e) & 1u) v += fmaxf(x, 0.f) + Ptmp;
        if ((winN >> e) & 1u) v -= fmaxf(-x, 0.f) + Ntmp;
        o[e] = v;
    }
    float4* pout = (float4*)(out + rowbase);
    float4 o0 = {o[0], o[1], o[2], o[3]};
    float4 o1 = {o[4], o[5], o[6], o[7]};
    pout[2 * tid]     = o0;
    pout[2 * tid + 1] = o1;
}

extern "C" void kernel_launch(void* const* d_in, const int* in_sizes, int n_in,
                              void* d_out, int out_size, void* d_ws, size_t ws_size,
                              hipStream_t stream)
{
    const float* x = (const float*)d_in[0];
    float* out = (float*)d_out;
    (void)in_sizes; (void)n_in; (void)d_ws; (void)ws_size; (void)out_size;
    kcomp_kernel<<<NROWS, 256, 0, stream>>>(x, out);
}

// Round 2
// 132.211 us; speedup vs baseline: 1.1452x; 1.1452x over previous
//
#include <hip/hip_runtime.h>

#define NROWS  16384
#define DIM    2048
#define KSEL   64          // TOPK/2 per side
#define FACTOR 6.26f

// Monotone order-preserving float->uint transform:
// ascending x  <=>  ascending u ; all negatives < all positives.
__device__ __forceinline__ unsigned f2ord(float f) {
    unsigned b = __float_as_uint(f);
    unsigned m = ((unsigned)((int)b >> 31)) | 0x80000000u;
    return b ^ m;
}

// Bank swizzle: bijective within each 16-bin run; makes the strided scan
// reads conflict-free while keeping consecutive digits on distinct banks.
__device__ __forceinline__ int hmap(unsigned b) {
    return (int)((b & ~15u) | ((b ^ (b >> 5)) & 15u));
}

// Exclusive scan over the 256 threads' values (rare exact-tie path only).
__device__ int excl_scan256(int v, unsigned* hist) {
    const int tid = threadIdx.x;
    __syncthreads();
    hist[tid] = (unsigned)v;
    __syncthreads();
    for (int off = 1; off < 256; off <<= 1) {
        unsigned t = (tid >= off) ? hist[tid - off] : 0u;
        __syncthreads();
        hist[tid] += t;
        __syncthreads();
    }
    return (int)hist[tid] - v;
}

__global__ __launch_bounds__(256)
void kcomp_kernel(const float* __restrict__ xin, float* __restrict__ out)
{
    __shared__ unsigned hist[4096];   // pass0: 4096 bins; pass1/2: P in [0,1024), N in [1024,2048)
    __shared__ int shd[8];            // P: D,need,eqc @0..2 ; N: @4..6
    __shared__ unsigned wsum[4];
    __shared__ float redf[8];

    const int tid  = threadIdx.x;
    const int lane = tid & 63;
    const int wid  = tid >> 6;
    const size_t rowbase = (size_t)blockIdx.x * DIM;
    const float4* pin = (const float4*)(xin + rowbase);

    float4 a = pin[2 * tid];
    float4 b = pin[2 * tid + 1];
    float xv[8] = {a.x, a.y, a.z, a.w, b.x, b.y, b.z, b.w};
    unsigned u[8];
    #pragma unroll
    for (int e = 0; e < 8; ++e) u[e] = f2ord(xv[e]);

    uint4* h4 = (uint4*)hist;
    const uint4 z4 = {0u, 0u, 0u, 0u};

    // ---------------- pass 0 : 12-bit digit (u>>20), one shared histogram serves BOTH sides
    #pragma unroll
    for (int i = 0; i < 4; ++i) h4[tid + 256 * i] = z4;
    __syncthreads();
    #pragma unroll
    for (int e = 0; e < 8; ++e) atomicAdd(&hist[hmap(u[e] >> 20)], 1u);
    __syncthreads();

    unsigned loc[16];
    unsigned L = 0;
    #pragma unroll
    for (int i = 0; i < 16; ++i) {
        loc[i] = hist[(tid << 4) | (i ^ ((tid >> 1) & 15))];
        L += loc[i];
    }
    unsigned sc = L;                              // intra-wave inclusive scan
    #pragma unroll
    for (int off = 1; off < 64; off <<= 1) {
        unsigned v = __shfl_up(sc, off);
        if (lane >= off) sc += v;
    }
    if (lane == 63) wsum[wid] = sc;
    __syncthreads();
    unsigned base = sc - L;
    #pragma unroll
    for (int w = 0; w < 4; ++w) if (w < wid) base += wsum[w];
    {
        const unsigned TN = KSEL;                 // crossing target for N (bottom-64)
        const unsigned TP = DIM - KSEL + 1;       // crossing target for P (top-64) = 1985
        unsigned acc = base;
        #pragma unroll
        for (int i = 0; i < 16; ++i) {
            unsigned h = loc[i], acc2 = acc + h;
            if (acc < TN && TN <= acc2) { shd[4] = (tid << 4) | i; shd[5] = (int)(TN - acc);        shd[6] = (int)h; }
            if (acc < TP && TP <= acc2) { shd[0] = (tid << 4) | i; shd[1] = (int)(acc2 - (TP - 1)); shd[2] = (int)h; }
            acc = acc2;
        }
    }
    __syncthreads();
    int Dp = shd[0], needP = shd[1], eqcP = shd[2];
    int Dn = shd[4], needN = shd[5], eqcN = shd[6];

    // ---------------- pass 1 : 10-bit digit (u>>10)&1023, both sides in parallel
    #pragma unroll
    for (int i = 0; i < 2; ++i) h4[tid + 256 * i] = z4;
    __syncthreads();
    #pragma unroll
    for (int e = 0; e < 8; ++e) {
        int d0 = (int)(u[e] >> 20);
        unsigned d1 = (u[e] >> 10) & 1023u;
        if (d0 == Dp) atomicAdd(&hist[hmap(d1)], 1u);
        if (d0 == Dn) atomicAdd(&hist[1024 + hmap(d1)], 1u);
    }
    __syncthreads();
    if (wid < 2) {                                // wave0: P, wave1: N — intra-wave only
        unsigned* hh = hist + (wid << 10);
        const unsigned T = wid ? (unsigned)needN : (unsigned)(eqcP - needP + 1);
        unsigned loc1[16]; unsigned L1 = 0;
        #pragma unroll
        for (int i = 0; i < 16; ++i) {
            loc1[i] = hh[(lane << 4) | (i ^ ((lane >> 1) & 15))];
            L1 += loc1[i];
        }
        unsigned sc1 = L1;
        #pragma unroll
        for (int off = 1; off < 64; off <<= 1) {
            unsigned v = __shfl_up(sc1, off);
            if (lane >= off) sc1 += v;
        }
        unsigned acc = sc1 - L1;
        const int o = wid ? 4 : 0;
        #pragma unroll
        for (int i = 0; i < 16; ++i) {
            unsigned h = loc1[i], acc2 = acc + h;
            if (acc < T && T <= acc2) {
                shd[o + 0] = (lane << 4) | i;
                shd[o + 1] = wid ? (int)(T - acc) : (int)(acc2 - (T - 1));
                shd[o + 2] = (int)h;
            }
            acc = acc2;
        }
    }
    __syncthreads();
    int Dp1 = shd[0]; needP = shd[1]; eqcP = shd[2];
    int Dn1 = shd[4]; needN = shd[5]; eqcN = shd[6];
    const unsigned upP = ((unsigned)Dp << 10) | (unsigned)Dp1;   // top 22 bits
    const unsigned upN = ((unsigned)Dn << 10) | (unsigned)Dn1;

    // ---------------- pass 2 : final 10 bits, both sides in parallel
    #pragma unroll
    for (int i = 0; i < 2; ++i) h4[tid + 256 * i] = z4;
    __syncthreads();
    #pragma unroll
    for (int e = 0; e < 8; ++e) {
        unsigned hi = u[e] >> 10;
        unsigned d2 = u[e] & 1023u;
        if (hi == upP) atomicAdd(&hist[hmap(d2)], 1u);
        if (hi == upN) atomicAdd(&hist[1024 + hmap(d2)], 1u);
    }
    __syncthreads();
    if (wid < 2) {
        unsigned* hh = hist + (wid << 10);
        const unsigned T = wid ? (unsigned)needN : (unsigned)(eqcP - needP + 1);
        unsigned loc1[16]; unsigned L1 = 0;
        #pragma unroll
        for (int i = 0; i < 16; ++i) {
            loc1[i] = hh[(lane << 4) | (i ^ ((lane >> 1) & 15))];
            L1 += loc1[i];
        }
        unsigned sc1 = L1;
        #pragma unroll
        for (int off = 1; off < 64; off <<= 1) {
            unsigned v = __shfl_up(sc1, off);
            if (lane >= off) sc1 += v;
        }
        unsigned acc = sc1 - L1;
        const int o = wid ? 4 : 0;
        #pragma unroll
        for (int i = 0; i < 16; ++i) {
            unsigned h = loc1[i], acc2 = acc + h;
            if (acc < T && T <= acc2) {
                shd[o + 0] = (lane << 4) | i;
                shd[o + 1] = wid ? (int)(T - acc) : (int)(acc2 - (T - 1));
                shd[o + 2] = (int)h;
            }
            acc = acc2;
        }
    }
    __syncthreads();
    int Dp2 = shd[0]; needP = shd[1]; eqcP = shd[2];
    int Dn2 = shd[4]; needN = shd[5]; eqcN = shd[6];

    const unsigned Tp = (upP << 10) | (unsigned)Dp2;   // exact 32-bit thresholds
    const unsigned Tn = (upN << 10) | (unsigned)Dn2;

    // ---------------- classify ----------------
    unsigned winP = 0, winN = 0;
    if (eqcP == needP) {                   // fast path: all ties included
        #pragma unroll
        for (int e = 0; e < 8; ++e) if (u[e] >= Tp) winP |= 1u << e;
    } else {                               // exact lowest-index tie-break (rare)
        int myeq = 0;
        #pragma unroll
        for (int e = 0; e < 8; ++e) myeq += (u[e] == Tp);
        int rbase = excl_scan256(myeq, hist);
        #pragma unroll
        for (int e = 0; e < 8; ++e) {
            if (u[e] > Tp) winP |= 1u << e;
            else if (u[e] == Tp) { if (rbase < needP) winP |= 1u << e; ++rbase; }
        }
    }
    if (eqcN == needN) {
        #pragma unroll
        for (int e = 0; e < 8; ++e) if (u[e] <= Tn) winN |= 1u << e;
    } else {
        int myeq = 0;
        #pragma unroll
        for (int e = 0; e < 8; ++e) myeq += (u[e] == Tn);
        int rbase = excl_scan256(myeq, hist);
        #pragma unroll
        for (int e = 0; e < 8; ++e) {
            if (u[e] < Tn) winN |= 1u << e;
            else if (u[e] == Tn) { if (rbase < needN) winN |= 1u << e; ++rbase; }
        }
    }

    // ---------------- loser energy (fused dual block-sum) ----------------
    float lp = 0.f, ln = 0.f;
    #pragma unroll
    for (int e = 0; e < 8; ++e) {
        float x = xv[e];
        if (!((winP >> e) & 1u)) lp += fmaxf(x, 0.f);
        if (!((winN >> e) & 1u)) ln += fmaxf(-x, 0.f);
    }
    #pragma unroll
    for (int off = 32; off; off >>= 1) {
        lp += __shfl_down(lp, off);
        ln += __shfl_down(ln, off);
    }
    __syncthreads();
    if (lane == 0) { redf[wid] = lp; redf[4 + wid] = ln; }
    __syncthreads();
    float Ptmp = FACTOR * (redf[0] + redf[1] + redf[2] + redf[3]);
    float Ntmp = FACTOR * (redf[4] + redf[5] + redf[6] + redf[7]);

    // ---------------- output ----------------
    float o[8];
    #pragma unroll
    for (int e = 0; e < 8; ++e) {
        float x = xv[e];
        float v = 0.f;
        if ((winP >> e) & 1u) v += fmaxf(x, 0.f) + Ptmp;
        if ((winN >> e) & 1u) v -= fmaxf(-x, 0.f) + Ntmp;
        o[e] = v;
    }
    float4* pout = (float4*)(out + rowbase);
    float4 o0 = {o[0], o[1], o[2], o[3]};
    float4 o1 = {o[4], o[5], o[6], o[7]};
    pout[2 * tid]     = o0;
    pout[2 * tid + 1] = o1;
}

extern "C" void kernel_launch(void* const* d_in, const int* in_sizes, int n_in,
                              void* d_out, int out_size, void* d_ws, size_t ws_size,
                              hipStream_t stream)
{
    const float* x = (const float*)d_in[0];
    float* out = (float*)d_out;
    (void)in_sizes; (void)n_in; (void)d_ws; (void)ws_size; (void)out_size;
    kcomp_kernel<<<NROWS, 256, 0, stream>>>(x, out);
}

// Round 3
// 77.761 us; speedup vs baseline: 1.9471x; 1.7002x over previous
//
#include <hip/hip_runtime.h>

#define NROWS  16384
#define DIM    2048
#define KSEL   64          // TOPK/2 per side
#define FACTOR 6.26f
#define CAP    256         // per-side tie-candidate capacity (mean ~35, >=16-sigma margin)

// Monotone order-preserving float->uint transform:
// ascending x  <=>  ascending u ; all negatives < all positives.
__device__ __forceinline__ unsigned f2ord(float f) {
    unsigned b = __float_as_uint(f);
    unsigned m = ((unsigned)((int)b >> 31)) | 0x80000000u;
    return b ^ m;
}

__global__ __launch_bounds__(256)
void kcomp_kernel(const float* __restrict__ xin, float* __restrict__ out)
{
    __shared__ unsigned hist32[1024];      // 2048 u16 bins, packed pairs (4 KB)
    __shared__ unsigned cand[2][CAP];      // packed (keyLow21<<11)|(2047-idx)
    __shared__ unsigned wbits[2][64];      // winner bitmask over 2048 elements
    __shared__ int      cnt[2];
    __shared__ int      shd[8];            // P: D,need,eqc @0..2 ; N: @4..6
    __shared__ unsigned wsum[4];
    __shared__ float    redf[8];

    const int tid  = threadIdx.x;
    const int lane = tid & 63;
    const int wid  = tid >> 6;
    const size_t rowbase = (size_t)blockIdx.x * DIM;
    const float4* pin = (const float4*)(xin + rowbase);

    // thread t owns consecutive elements [8t, 8t+8)
    float4 va = pin[2 * tid];
    float4 vb = pin[2 * tid + 1];
    float xv[8] = {va.x, va.y, va.z, va.w, vb.x, vb.y, vb.z, vb.w};
    unsigned u[8];
    #pragma unroll
    for (int e = 0; e < 8; ++e) u[e] = f2ord(xv[e]);

    // ---- clear (one shot) ----
    ((uint4*)hist32)[tid] = (uint4){0u, 0u, 0u, 0u};
    if (tid < 128) ((unsigned*)wbits)[tid] = 0u;
    if (tid < 2)   cnt[tid] = 0;
    __syncthreads();

    // ---- single histogram pass: 11-bit digit (u>>21), serves BOTH sides ----
    #pragma unroll
    for (int e = 0; e < 8; ++e) {
        unsigned d = u[e] >> 21;
        atomicAdd(&hist32[d >> 1], 1u << ((d & 1u) << 4));
    }
    __syncthreads();

    // ---- scan: thread t owns bins [8t,8t+8) = words [4t,4t+4) (contiguous b128 read) ----
    uint4 hv = ((const uint4*)hist32)[tid];
    unsigned bn[8];
    bn[0] = hv.x & 0xffffu; bn[1] = hv.x >> 16;
    bn[2] = hv.y & 0xffffu; bn[3] = hv.y >> 16;
    bn[4] = hv.z & 0xffffu; bn[5] = hv.z >> 16;
    bn[6] = hv.w & 0xffffu; bn[7] = hv.w >> 16;
    unsigned L = bn[0]+bn[1]+bn[2]+bn[3]+bn[4]+bn[5]+bn[6]+bn[7];
    unsigned sc = L;
    #pragma unroll
    for (int off = 1; off < 64; off <<= 1) {
        unsigned v = __shfl_up(sc, off);
        if (lane >= off) sc += v;
    }
    if (lane == 63) wsum[wid] = sc;
    __syncthreads();
    unsigned base = sc - L;
    #pragma unroll
    for (int w = 0; w < 4; ++w) if (w < wid) base += wsum[w];
    {
        const unsigned TN = KSEL;                // crossing target, N (bottom-64)
        const unsigned TP = DIM - KSEL + 1;      // crossing target, P (top-64) = 1985
        unsigned acc = base;
        #pragma unroll
        for (int i = 0; i < 8; ++i) {
            unsigned h = bn[i], acc2 = acc + h;
            if (acc < TN && TN <= acc2) { shd[4] = (tid << 3) | i; shd[5] = (int)(TN - acc);        shd[6] = (int)h; }
            if (acc < TP && TP <= acc2) { shd[0] = (tid << 3) | i; shd[1] = (int)(acc2 - (TP - 1)); shd[2] = (int)h; }
            acc = acc2;
        }
    }
    __syncthreads();
    const int Dp = shd[0], needP = shd[1], eqcP = shd[2];
    const int Dn = shd[4], needN = shd[5], eqcN = shd[6];
    const bool fastP = (eqcP == needP);          // all tie-bin members win
    const bool fastN = (eqcN == needN);

    // ---- classify plain winners + gather tie candidates ----
    unsigned winP = 0, winN = 0;
    #pragma unroll
    for (int e = 0; e < 8; ++e) {
        const int d = (int)(u[e] >> 21);
        if (d > Dp) winP |= 1u << e;
        else if (d == Dp) {
            if (fastP) winP |= 1u << e;
            else {
                int s = atomicAdd(&cnt[0], 1);
                unsigned idx = (unsigned)((tid << 3) | e);
                if (s < CAP) cand[0][s] = ((u[e] & 0x1FFFFFu) << 11) | (2047u - idx);
            }
        }
        if (d < Dn) winN |= 1u << e;
        else if (d == Dn) {
            if (fastN) winN |= 1u << e;
            else {
                int s = atomicAdd(&cnt[1], 1);
                unsigned idx = (unsigned)((tid << 3) | e);
                if (s < CAP) cand[1][s] = (((~u[e]) & 0x1FFFFFu) << 11) | (2047u - idx);
            }
        }
    }
    __syncthreads();

    // ---- rank tie candidates: wave 0 -> P, wave 1 -> N ----
    // Packed keys are unique (idx is unique) -> ranks are a permutation, exact
    // lowest-index tie-break is encoded in (2047-idx).
    if (wid < 2) {
        const int side = wid;
        const bool fast = side ? fastN : fastP;
        if (!fast) {
            const int eqc  = side ? eqcN : eqcP;
            const int need = side ? needN : needP;
            const int ec   = min(eqc, CAP);
            for (int j = lane; j < ec; j += 64) {
                const unsigned mine = cand[side][j];
                int rank = 0;
                for (int s = 0; s < ec; ++s)          // broadcast LDS reads
                    rank += (cand[side][s] > mine);
                if (rank < need) {
                    unsigned idx = 2047u - (mine & 2047u);
                    atomicOr(&wbits[side][idx >> 5], 1u << (idx & 31u));
                }
            }
        }
    }
    __syncthreads();

    // ---- merge tie winners (one word covers 4 threads' 8-element bytes) ----
    {
        unsigned wpw = wbits[0][tid >> 2];
        unsigned wnw = wbits[1][tid >> 2];
        unsigned sh = (tid & 3u) << 3;
        winP |= (wpw >> sh) & 0xffu;
        winN |= (wnw >> sh) & 0xffu;
    }

    // ---- loser energy (fused dual block-sum) ----
    float lp = 0.f, ln = 0.f;
    #pragma unroll
    for (int e = 0; e < 8; ++e) {
        float x = xv[e];
        if (!((winP >> e) & 1u)) lp += fmaxf(x, 0.f);
        if (!((winN >> e) & 1u)) ln += fmaxf(-x, 0.f);
    }
    #pragma unroll
    for (int off = 32; off; off >>= 1) {
        lp += __shfl_down(lp, off);
        ln += __shfl_down(ln, off);
    }
    if (lane == 0) { redf[wid] = lp; redf[4 + wid] = ln; }
    __syncthreads();
    float Ptmp = FACTOR * (redf[0] + redf[1] + redf[2] + redf[3]);
    float Ntmp = FACTOR * (redf[4] + redf[5] + redf[6] + redf[7]);

    // ---- output ----
    float o[8];
    #pragma unroll
    for (int e = 0; e < 8; ++e) {
        float x = xv[e];
        float v = 0.f;
        if ((winP >> e) & 1u) v += fmaxf(x, 0.f) + Ptmp;
        if ((winN >> e) & 1u) v -= fmaxf(-x, 0.f) + Ntmp;
        o[e] = v;
    }
    float4* pout = (float4*)(out + rowbase);
    float4 o0 = {o[0], o[1], o[2], o[3]};
    float4 o1 = {o[4], o[5], o[6], o[7]};
    pout[2 * tid]     = o0;
    pout[2 * tid + 1] = o1;
}

extern "C" void kernel_launch(void* const* d_in, const int* in_sizes, int n_in,
                              void* d_out, int out_size, void* d_ws, size_t ws_size,
                              hipStream_t stream)
{
    const float* x = (const float*)d_in[0];
    float* out = (float*)d_out;
    (void)in_sizes; (void)n_in; (void)d_ws; (void)ws_size; (void)out_size;
    kcomp_kernel<<<NROWS, 256, 0, stream>>>(x, out);
}